// Round 1
// baseline (1616.191 us; speedup 1.0000x reference)
//
#include <hip/hip_runtime.h>
#include <hip/hip_bf16.h>
#include <cstdint>
#include <cstddef>

// Problem constants (from reference)
#define T_TOK 2048
#define HID   4096
#define VOC   32000
#define NLORA 8
#define RANK  16
#define KAUG  4224   // HID + NLORA*RANK

typedef __attribute__((ext_vector_type(8))) short short8;
typedef __attribute__((ext_vector_type(4))) float floatx4;

typedef const __attribute__((address_space(1))) void gvoid_t;
typedef __attribute__((address_space(3))) void lvoid_t;

__device__ __forceinline__ unsigned short f2bf(float f) {
    unsigned u = __float_as_uint(f);
    u += 0x7fffu + ((u >> 16) & 1u);   // round-to-nearest-even
    return (unsigned short)(u >> 16);
}

// ---------------------------------------------------------------------------
// Kernel 1: per token t -- convert X row to bf16, compute xa[t,:] = X[t]·A[e]^T
// (fp32 accum), scatter xa into the 128 augmented columns (zeros elsewhere).
// One block per token, 4 waves; wave w computes ranks w*4..w*4+3.
// ---------------------------------------------------------------------------
__global__ __launch_bounds__(256)
void prep_x_kernel(const float* __restrict__ X, const float* __restrict__ A,
                   const int* __restrict__ idx, unsigned short* __restrict__ Xaug) {
    const int t = blockIdx.x;
    const int e = idx[t];
    const float* xrow = X + (size_t)t * HID;
    unsigned short* orow = Xaug + (size_t)t * KAUG;

    // bf16 conversion of the 4096 main columns (vectorized 4 at a time)
    for (int i = threadIdx.x; i < HID / 4; i += 256) {
        float4 v = reinterpret_cast<const float4*>(xrow)[i];
        ushort4 o;
        o.x = f2bf(v.x); o.y = f2bf(v.y); o.z = f2bf(v.z); o.w = f2bf(v.w);
        reinterpret_cast<ushort4*>(orow)[i] = o;
    }

    // xa = x . A[e]^T  (16 dots of length 4096)
    __shared__ float xa_s[RANK];
    const int wave = threadIdx.x >> 6;
    const int lane = threadIdx.x & 63;
    const float* Ab = A + (size_t)e * RANK * HID;
    const float* a0p = Ab + (size_t)(wave * 4 + 0) * HID;
    const float* a1p = Ab + (size_t)(wave * 4 + 1) * HID;
    const float* a2p = Ab + (size_t)(wave * 4 + 2) * HID;
    const float* a3p = Ab + (size_t)(wave * 4 + 3) * HID;

    float p0 = 0.f, p1 = 0.f, p2 = 0.f, p3 = 0.f;
    for (int h4 = lane; h4 < HID / 4; h4 += 64) {
        float4 xv = reinterpret_cast<const float4*>(xrow)[h4];
        float4 a0 = reinterpret_cast<const float4*>(a0p)[h4];
        float4 a1 = reinterpret_cast<const float4*>(a1p)[h4];
        float4 a2 = reinterpret_cast<const float4*>(a2p)[h4];
        float4 a3 = reinterpret_cast<const float4*>(a3p)[h4];
        p0 += xv.x * a0.x + xv.y * a0.y + xv.z * a0.z + xv.w * a0.w;
        p1 += xv.x * a1.x + xv.y * a1.y + xv.z * a1.z + xv.w * a1.w;
        p2 += xv.x * a2.x + xv.y * a2.y + xv.z * a2.z + xv.w * a2.w;
        p3 += xv.x * a3.x + xv.y * a3.y + xv.z * a3.z + xv.w * a3.w;
    }
    #pragma unroll
    for (int off = 32; off; off >>= 1) {
        p0 += __shfl_down(p0, off);
        p1 += __shfl_down(p1, off);
        p2 += __shfl_down(p2, off);
        p3 += __shfl_down(p3, off);
    }
    if (lane == 0) {
        xa_s[wave * 4 + 0] = p0;
        xa_s[wave * 4 + 1] = p1;
        xa_s[wave * 4 + 2] = p2;
        xa_s[wave * 4 + 3] = p3;
    }
    __syncthreads();

    // augmented 128 columns: block e_t gets xa, other blocks zero
    if (threadIdx.x < NLORA * RANK) {
        int eb = threadIdx.x >> 4, r = threadIdx.x & 15;
        float v = (eb == e) ? xa_s[r] : 0.f;
        orow[HID + threadIdx.x] = f2bf(v);
    }
}

// ---------------------------------------------------------------------------
// Kernel 2: build a chunk of Waug (rows v0..v0+nrows-1):
//   cols 0..4095   = bf16(W[v, :])
//   cols 4096+e*16+r = bf16(B[e, v, r])
// ---------------------------------------------------------------------------
__global__ __launch_bounds__(256)
void prep_w_kernel(const float* __restrict__ W, const float* __restrict__ B,
                   unsigned short* __restrict__ Waug, int v0, int nrows) {
    for (int vi = blockIdx.x; vi < nrows; vi += gridDim.x) {
        const int v = v0 + vi;
        const float* wrow = W + (size_t)v * HID;
        unsigned short* orow = Waug + (size_t)vi * KAUG;
        for (int i = threadIdx.x; i < HID / 4; i += 256) {
            float4 x = reinterpret_cast<const float4*>(wrow)[i];
            ushort4 o;
            o.x = f2bf(x.x); o.y = f2bf(x.y); o.z = f2bf(x.z); o.w = f2bf(x.w);
            reinterpret_cast<ushort4*>(orow)[i] = o;
        }
        if (threadIdx.x < NLORA * RANK) {
            int e = threadIdx.x >> 4, r = threadIdx.x & 15;
            orow[HID + threadIdx.x] = f2bf(B[((size_t)e * VOC + v) * RANK + r]);
        }
    }
}

// ---------------------------------------------------------------------------
// Kernel 3: C[t, v0+v] = Xaug[t,:] . Waug[v,:]   (A*B^T, both K-major bf16)
// m97-style: 128x128 tile, BK=64, 4 waves each 64x64, global_load_lds(16B)
// staging into linear LDS, mfma_f32_16x16x32_bf16, fp32 accum.
// grid = 16 * ntilesV blocks; tm = bid & 15 (fastest -> W-tile sharing).
// ---------------------------------------------------------------------------
#define BM 128
#define BN 128
#define BKK 64

__global__ __launch_bounds__(256)
void gemm_kernel(const unsigned short* __restrict__ Xa,
                 const unsigned short* __restrict__ Wa,
                 float* __restrict__ C, int v0) {
    __shared__ unsigned short As[BM * BKK];
    __shared__ unsigned short Bs[BN * BKK];

    const int bid = blockIdx.x;
    const int tm = bid & 15;   // 2048/128 = 16 M tiles
    const int tv = bid >> 4;
    const int tid = threadIdx.x;
    const int lane = tid & 63;
    const int wave = tid >> 6;
    const int wr = wave >> 1, wc = wave & 1;

    const int rm = tm * BM;        // token row base
    const int rv = tv * BN;        // chunk-local vocab row base

    // staging map: idx16 = it*256+tid; row = idx16>>3; col = (idx16&7)*8
    const unsigned short* gA[4];
    const unsigned short* gB[4];
    unsigned short* lA[4];
    unsigned short* lB[4];
    #pragma unroll
    for (int it = 0; it < 4; ++it) {
        int idx16 = it * 256 + tid;
        int row = idx16 >> 3;
        int col = (idx16 & 7) * 8;
        gA[it] = Xa + (size_t)(rm + row) * KAUG + col;
        gB[it] = Wa + (size_t)(rv + row) * KAUG + col;
        lA[it] = &As[idx16 * 8];
        lB[it] = &Bs[idx16 * 8];
    }

    floatx4 acc[4][4];
    #pragma unroll
    for (int m = 0; m < 4; ++m)
        #pragma unroll
        for (int n = 0; n < 4; ++n)
            acc[m][n] = (floatx4){0.f, 0.f, 0.f, 0.f};

    const int aoff = (wr * 64 + (lane & 15)) * BKK + (lane >> 4) * 8;
    const int boff = (wc * 64 + (lane & 15)) * BKK + (lane >> 4) * 8;

    for (int k0 = 0; k0 < KAUG; k0 += BKK) {
        #pragma unroll
        for (int it = 0; it < 4; ++it)
            __builtin_amdgcn_global_load_lds((gvoid_t*)(gA[it] + k0), (lvoid_t*)lA[it], 16, 0, 0);
        #pragma unroll
        for (int it = 0; it < 4; ++it)
            __builtin_amdgcn_global_load_lds((gvoid_t*)(gB[it] + k0), (lvoid_t*)lB[it], 16, 0, 0);
        __syncthreads();

        short8 a[4][2], b[4][2];
        #pragma unroll
        for (int m = 0; m < 4; ++m) {
            a[m][0] = *reinterpret_cast<const short8*>(&As[aoff + m * 16 * BKK]);
            a[m][1] = *reinterpret_cast<const short8*>(&As[aoff + m * 16 * BKK + 32]);
        }
        #pragma unroll
        for (int n = 0; n < 4; ++n) {
            b[n][0] = *reinterpret_cast<const short8*>(&Bs[boff + n * 16 * BKK]);
            b[n][1] = *reinterpret_cast<const short8*>(&Bs[boff + n * 16 * BKK + 32]);
        }
        #pragma unroll
        for (int ks = 0; ks < 2; ++ks)
            #pragma unroll
            for (int m = 0; m < 4; ++m)
                #pragma unroll
                for (int n = 0; n < 4; ++n)
                    acc[m][n] = __builtin_amdgcn_mfma_f32_16x16x32_bf16(
                        a[m][ks], b[n][ks], acc[m][n], 0, 0, 0);
        __syncthreads();
    }

    // epilogue: C/D layout col = lane&15, row = (lane>>4)*4 + j   [m89-verified]
    const int crow0 = rm + wr * 64 + (lane >> 4) * 4;
    const int ccol0 = v0 + tv * BN + wc * 64 + (lane & 15);
    #pragma unroll
    for (int m = 0; m < 4; ++m)
        #pragma unroll
        for (int n = 0; n < 4; ++n)
            #pragma unroll
            for (int j = 0; j < 4; ++j)
                C[(size_t)(crow0 + m * 16 + j) * VOC + ccol0 + n * 16] = acc[m][n][j];
}

// ---------------------------------------------------------------------------
extern "C" void kernel_launch(void* const* d_in, const int* in_sizes, int n_in,
                              void* d_out, int out_size, void* d_ws, size_t ws_size,
                              hipStream_t stream) {
    (void)in_sizes; (void)n_in; (void)out_size;
    const float* X  = (const float*)d_in[0];   // [2048, 4096]
    const float* W  = (const float*)d_in[1];   // [32000, 4096]
    const float* A  = (const float*)d_in[2];   // [8, 16, 4096]
    const float* B  = (const float*)d_in[3];   // [8, 32000, 16]
    const int* idx  = (const int*)d_in[4];     // [2048]
    float* out      = (float*)d_out;           // [2048, 32000] fp32

    unsigned short* Xaug = (unsigned short*)d_ws;
    const size_t xaug_elems = (size_t)T_TOK * KAUG;          // 17.3 MB as bf16
    unsigned short* Waug = Xaug + xaug_elems;
    const size_t avail = (ws_size > xaug_elems * 2) ? ws_size - xaug_elems * 2 : 0;

    // Pick V-chunking (tiles of 128 vocab rows per chunk) to fit Waug in ws.
    // ws_size is constant across calls -> same decomposition every call (graph-safe).
    const int cand[] = {250, 125, 50, 25, 10, 5, 2, 1};
    int tilesPerChunk = 1;
    for (int ci = 0; ci < 8; ++ci) {
        size_t need = (size_t)cand[ci] * 128 * KAUG * 2;
        if (need <= avail) { tilesPerChunk = cand[ci]; break; }
    }

    prep_x_kernel<<<T_TOK, 256, 0, stream>>>(X, A, idx, Xaug);

    int done = 0;
    while (done < 250) {
        int tiles = tilesPerChunk;
        if (tiles > 250 - done) tiles = 250 - done;
        int v0 = done * 128;
        int nrows = tiles * 128;
        int pgrid = nrows < 2048 ? nrows : 2048;
        prep_w_kernel<<<pgrid, 256, 0, stream>>>(W, B, Waug, v0, nrows);
        gemm_kernel<<<16 * tiles, 256, 0, stream>>>(Xaug, Waug, out, v0);
        done += tiles;
    }
}